// Round 1
// baseline (627.252 us; speedup 1.0000x reference)
//
#include <hip/hip_runtime.h>
#include <math.h>

#define NN 50000
#define NE 800000
#define INF 256
#define HF 64
#define OUTF 320   // 5 * 64

// ---------------- theta (compile-time-ish, computed on host each launch) ----
struct ThetaM { float m[5][7]; };

static void compute_theta(ThetaM& tm) {
    const double e = 1.4;
    auto fact = [](int n) { double r = 1.0; for (int i = 2; i <= n; ++i) r *= i; return r; };
    for (int t = 0; t < 5; ++t) {
        int i = t + 2;              // i in [2,6]
        int mm = 6 - i;             // d - i + OFFSET
        double B = fact(i) * fact(6 - i) / fact(7);   // beta(i+1, 7-i)
        for (int k = 0; k < 7; ++k) tm.m[t][k] = 0.f;
        for (int j = 0; j <= mm; ++j) {
            double cb = fact(mm) / (fact(j) * fact(mm - j));
            double v = pow(1.0 / e, (double)i) * cb * pow(-1.0 / e, (double)j) / (e * B);
            tm.m[t][i + j] = (float)v;
        }
    }
}

// ---------------- kernels ---------------------------------------------------
__global__ __launch_bounds__(256) void count_kernel(const int* __restrict__ src,
                                                    const int* __restrict__ dst,
                                                    int* __restrict__ cnt_src,
                                                    int* __restrict__ cnt_dst) {
    int e = blockIdx.x * 256 + threadIdx.x;
    if (e < NE) {
        atomicAdd(&cnt_src[src[e]], 1);
        atomicAdd(&cnt_dst[dst[e]], 1);
    }
}

__global__ __launch_bounds__(256) void dinv_kernel(const int* __restrict__ cnt_src,
                                                   float* __restrict__ dinv) {
    int i = blockIdx.x * 256 + threadIdx.x;
    if (i < NN) {
        float d = (float)cnt_src[i];
        if (d < 1.f) d = 1.f;
        dinv[i] = 1.0f / sqrtf(d);
    }
}

// single-block exclusive scan of cnt_dst -> row_ptr (and cursor copy)
__global__ __launch_bounds__(1024) void scan_kernel(const int* __restrict__ cnt,
                                                    int* __restrict__ row_ptr,
                                                    int* __restrict__ cursor) {
    __shared__ int s[1024];
    int tid = threadIdx.x;
    const int CH = 49;                // 1024*49 = 50176 >= NN
    int base = tid * CH;
    int sum = 0;
    for (int i = 0; i < CH; ++i) {
        int idx = base + i;
        if (idx < NN) sum += cnt[idx];
    }
    s[tid] = sum;
    __syncthreads();
    for (int off = 1; off < 1024; off <<= 1) {
        int t = (tid >= off) ? s[tid - off] : 0;
        __syncthreads();
        s[tid] += t;
        __syncthreads();
    }
    int run = (tid == 0) ? 0 : s[tid - 1];
    for (int i = 0; i < CH; ++i) {
        int idx = base + i;
        if (idx < NN) {
            row_ptr[idx] = run;
            cursor[idx]  = run;
            run += cnt[idx];
        }
    }
    if (tid == 1023) row_ptr[NN] = run;   // == NE
}

__global__ __launch_bounds__(256) void fill_kernel(const int* __restrict__ src,
                                                   const int* __restrict__ dst,
                                                   int* __restrict__ cursor,
                                                   int* __restrict__ col) {
    int e = blockIdx.x * 256 + threadIdx.x;
    if (e < NE) {
        int pos = atomicAdd(&cursor[dst[e]], 1);
        col[pos] = src[e];
    }
}

// h = leaky_relu(x @ W + b); f = h; g = h * dinv[row]
// block: 256 thr -> 64 rows x 64 cols tile, 4x4 register tile per thread
__global__ __launch_bounds__(256) void gemm_kernel(const float* __restrict__ x,
                                                   const float* __restrict__ W,
                                                   const float* __restrict__ b,
                                                   const float* __restrict__ dinv,
                                                   float* __restrict__ f,
                                                   float* __restrict__ g) {
    __shared__ __align__(16) float xs[64][33];
    __shared__ __align__(16) float ws[32][64];
    int tid = threadIdx.x;
    int row0 = blockIdx.x * 64;
    int tc = (tid & 15) * 4;
    int tr = (tid >> 4) * 4;
    float acc[4][4] = {};
    for (int kb = 0; kb < INF; kb += 32) {
        // stage x: 64 rows x 32 k = 512 float4
        for (int l = tid; l < 512; l += 256) {
            int r  = l >> 3;
            int kq = (l & 7) * 4;
            float4 v = make_float4(0.f, 0.f, 0.f, 0.f);
            int grow = row0 + r;
            if (grow < NN) v = *(const float4*)&x[(size_t)grow * INF + kb + kq];
            xs[r][kq + 0] = v.x; xs[r][kq + 1] = v.y; xs[r][kq + 2] = v.z; xs[r][kq + 3] = v.w;
        }
        // stage W chunk: rows kb..kb+31, all 64 cols (contiguous 2048 floats)
        for (int l = tid; l < 512; l += 256) {
            float4 v = *(const float4*)&W[kb * HF + l * 4];
            int kk = (l * 4) >> 6;
            int cc = (l * 4) & 63;
            ws[kk][cc + 0] = v.x; ws[kk][cc + 1] = v.y; ws[kk][cc + 2] = v.z; ws[kk][cc + 3] = v.w;
        }
        __syncthreads();
        #pragma unroll 8
        for (int k = 0; k < 32; ++k) {
            float4 wq = *(const float4*)&ws[k][tc];
            float wv0 = wq.x, wv1 = wq.y, wv2 = wq.z, wv3 = wq.w;
            #pragma unroll
            for (int i = 0; i < 4; ++i) {
                float xv = xs[tr + i][k];
                acc[i][0] += xv * wv0;
                acc[i][1] += xv * wv1;
                acc[i][2] += xv * wv2;
                acc[i][3] += xv * wv3;
            }
        }
        __syncthreads();
    }
    #pragma unroll
    for (int i = 0; i < 4; ++i) {
        int row = row0 + tr + i;
        if (row < NN) {
            float dv = dinv[row];
            #pragma unroll
            for (int jj = 0; jj < 4; ++jj) {
                int c = tc + jj;
                float h = acc[i][jj] + b[c];
                h = (h > 0.f) ? h : 0.01f * h;
                f[(size_t)row * HF + c] = h;
                g[(size_t)row * HF + c] = h * dv;
            }
        }
    }
}

// one wave per node; lane = feature. msg = sum_{j in row} g_in[col[j]];
// f_new = f - msg*dinv; g_out = f_new*dinv; optionally store f_new to out slot
__global__ __launch_bounds__(256) void prop_kernel(const int* __restrict__ row_ptr,
                                                   const int* __restrict__ col,
                                                   const float* __restrict__ dinv,
                                                   const float* __restrict__ g_in,
                                                   float* __restrict__ f,
                                                   float* __restrict__ g_out,
                                                   float* __restrict__ out_slot) {
    int wid = (blockIdx.x * 256 + threadIdx.x) >> 6;   // node
    int c = threadIdx.x & 63;                          // feature
    if (wid >= NN) return;
    int start = row_ptr[wid];
    int end   = row_ptr[wid + 1];
    float s = 0.f;
    int j = start;
    for (; j + 4 <= end; j += 4) {
        int c0 = col[j + 0] * HF;
        int c1 = col[j + 1] * HF;
        int c2 = col[j + 2] * HF;
        int c3 = col[j + 3] * HF;
        float a0 = g_in[c0 + c];
        float a1 = g_in[c1 + c];
        float a2 = g_in[c2 + c];
        float a3 = g_in[c3 + c];
        s += (a0 + a1) + (a2 + a3);
    }
    for (; j < end; ++j) s += g_in[col[j] * HF + c];
    float dv = dinv[wid];
    int idx = wid * HF + c;
    float fv = f[idx] - s * dv;
    f[idx] = fv;
    g_out[idx] = fv * dv;
    if (out_slot) out_slot[(size_t)wid * OUTF + c] = fv;
}

// out slot t currently holds f_{t+2}; apply upper-triangular theta combo in place
__global__ __launch_bounds__(256) void final_kernel(float* __restrict__ out, ThetaM tm) {
    int idx = blockIdx.x * 256 + threadIdx.x;          // over NN*64
    if (idx >= NN * HF) return;
    int n = idx >> 6;
    int c = idx & 63;
    float v[5];
    #pragma unroll
    for (int j = 0; j < 5; ++j) v[j] = out[(size_t)n * OUTF + j * HF + c];
    #pragma unroll
    for (int t = 0; t < 5; ++t) {
        float o = 0.f;
        #pragma unroll
        for (int j = 0; j < 5; ++j) {
            if (j >= t) o += tm.m[t][j + 2] * v[j];    // k = j+2
        }
        out[(size_t)n * OUTF + t * HF + c] = o;
    }
}

// ---------------- launch -----------------------------------------------------
extern "C" void kernel_launch(void* const* d_in, const int* in_sizes, int n_in,
                              void* d_out, int out_size, void* d_ws, size_t ws_size,
                              hipStream_t stream) {
    const float* x  = (const float*)d_in[0];
    const float* W  = (const float*)d_in[1];
    const float* b  = (const float*)d_in[2];
    const int* src  = (const int*)d_in[3];
    const int* dst  = (const int*)d_in[4];
    float* out = (float*)d_out;

    char* ws = (char*)d_ws;
    size_t off = 0;
    auto alloc = [&](size_t bytes) -> void* {
        void* p = ws + off;
        off += (bytes + 255) & ~(size_t)255;
        return p;
    };
    int*   cnt_src = (int*)alloc((size_t)NN * 4);
    int*   cnt_dst = (int*)alloc((size_t)NN * 4);
    int*   row_ptr = (int*)alloc((size_t)(NN + 1) * 4);
    int*   cursor  = (int*)alloc((size_t)NN * 4);
    float* dinv    = (float*)alloc((size_t)NN * 4);
    int*   col     = (int*)alloc((size_t)NE * 4);
    float* f       = (float*)alloc((size_t)NN * HF * 4);
    float* gA      = (float*)alloc((size_t)NN * HF * 4);
    float* gB      = (float*)alloc((size_t)NN * HF * 4);

    hipMemsetAsync(cnt_src, 0, (size_t)NN * 4, stream);
    hipMemsetAsync(cnt_dst, 0, (size_t)NN * 4, stream);

    count_kernel<<<(NE + 255) / 256, 256, 0, stream>>>(src, dst, cnt_src, cnt_dst);
    dinv_kernel<<<(NN + 255) / 256, 256, 0, stream>>>(cnt_src, dinv);
    scan_kernel<<<1, 1024, 0, stream>>>(cnt_dst, row_ptr, cursor);
    fill_kernel<<<(NE + 255) / 256, 256, 0, stream>>>(src, dst, cursor, col);
    gemm_kernel<<<(NN + 63) / 64, 256, 0, stream>>>(x, W, b, dinv, f, gA);

    float* gin = gA;
    float* gout = gB;
    for (int k = 1; k <= 6; ++k) {
        float* slot = (k >= 2) ? (out + (size_t)(k - 2) * HF) : nullptr;
        prop_kernel<<<(NN * HF + 255) / 256, 256, 0, stream>>>(row_ptr, col, dinv, gin, f, gout, slot);
        float* t = gin; gin = gout; gout = t;
    }

    ThetaM tm;
    compute_theta(tm);
    final_kernel<<<(NN * HF + 255) / 256, 256, 0, stream>>>(out, tm);
}

// Round 2
// 503.822 us; speedup vs baseline: 1.2450x; 1.2450x over previous
//
#include <hip/hip_runtime.h>
#include <math.h>

#define NN 50000
#define NE 800000
#define INF 256
#define HF 64
#define OUTF 320   // 5 * 64
#define NB ((NN + 255) / 256)   // 196 blocks for node-range kernels

// ---------------- theta (computed on host each launch) ----------------------
struct ThetaM { float m[5][7]; };

static void compute_theta(ThetaM& tm) {
    const double e = 1.4;
    auto fact = [](int n) { double r = 1.0; for (int i = 2; i <= n; ++i) r *= i; return r; };
    for (int t = 0; t < 5; ++t) {
        int i = t + 2;              // i in [2,6]
        int mm = 6 - i;             // d - i + OFFSET
        double B = fact(i) * fact(6 - i) / fact(7);   // beta(i+1, 7-i)
        for (int k = 0; k < 7; ++k) tm.m[t][k] = 0.f;
        for (int j = 0; j <= mm; ++j) {
            double cb = fact(mm) / (fact(j) * fact(mm - j));
            double v = pow(1.0 / e, (double)i) * cb * pow(-1.0 / e, (double)j) / (e * B);
            tm.m[t][i + j] = (float)v;
        }
    }
}

// ---------------- kernels ---------------------------------------------------
__global__ __launch_bounds__(256) void count_kernel(const int* __restrict__ src,
                                                    const int* __restrict__ dst,
                                                    int* __restrict__ cnt_src,
                                                    int* __restrict__ cnt_dst) {
    int e = blockIdx.x * 256 + threadIdx.x;
    if (e < NE) {
        atomicAdd(&cnt_src[src[e]], 1);
        atomicAdd(&cnt_dst[dst[e]], 1);
    }
}

__global__ __launch_bounds__(256) void dinv_kernel(const int* __restrict__ cnt_src,
                                                   float* __restrict__ dinv) {
    int i = blockIdx.x * 256 + threadIdx.x;
    if (i < NN) {
        float d = (float)cnt_src[i];
        if (d < 1.f) d = 1.f;
        dinv[i] = 1.0f / sqrtf(d);
    }
}

// ---- 3-stage multi-block exclusive scan of cnt_dst -> row_ptr/cursor -------
// Stage 1: per-block sum of 256 counts
__global__ __launch_bounds__(256) void scan_reduce_kernel(const int* __restrict__ cnt,
                                                          int* __restrict__ partial) {
    __shared__ int s[256];
    int tid = threadIdx.x;
    int gid = blockIdx.x * 256 + tid;
    s[tid] = (gid < NN) ? cnt[gid] : 0;
    __syncthreads();
    for (int off = 128; off > 0; off >>= 1) {
        if (tid < off) s[tid] += s[tid + off];
        __syncthreads();
    }
    if (tid == 0) partial[blockIdx.x] = s[0];
}

// Stage 2: single small block scans the NB partials -> exclusive block offsets
__global__ __launch_bounds__(256) void scan_partials_kernel(const int* __restrict__ partial,
                                                            int* __restrict__ offsets,
                                                            int* __restrict__ row_ptr) {
    __shared__ int s[256];
    int tid = threadIdx.x;
    s[tid] = (tid < NB) ? partial[tid] : 0;
    __syncthreads();
    // Hillis-Steele inclusive scan over 256
    for (int off = 1; off < 256; off <<= 1) {
        int t = (tid >= off) ? s[tid - off] : 0;
        __syncthreads();
        s[tid] += t;
        __syncthreads();
    }
    if (tid < NB) offsets[tid] = (tid == 0) ? 0 : s[tid - 1];
    if (tid == 0) row_ptr[NN] = NE;
}

// Stage 3: per-block local exclusive scan + block offset -> row_ptr & cursor
__global__ __launch_bounds__(256) void scan_write_kernel(const int* __restrict__ cnt,
                                                         const int* __restrict__ offsets,
                                                         int* __restrict__ row_ptr,
                                                         int* __restrict__ cursor) {
    __shared__ int s[256];
    int tid = threadIdx.x;
    int gid = blockIdx.x * 256 + tid;
    int c = (gid < NN) ? cnt[gid] : 0;
    s[tid] = c;
    __syncthreads();
    for (int off = 1; off < 256; off <<= 1) {
        int t = (tid >= off) ? s[tid - off] : 0;
        __syncthreads();
        s[tid] += t;
        __syncthreads();
    }
    if (gid < NN) {
        int v = offsets[blockIdx.x] + s[tid] - c;   // exclusive
        row_ptr[gid] = v;
        cursor[gid]  = v;
    }
}

__global__ __launch_bounds__(256) void fill_kernel(const int* __restrict__ src,
                                                   const int* __restrict__ dst,
                                                   int* __restrict__ cursor,
                                                   int* __restrict__ col) {
    int e = blockIdx.x * 256 + threadIdx.x;
    if (e < NE) {
        int pos = atomicAdd(&cursor[dst[e]], 1);
        col[pos] = src[e];
    }
}

// h = leaky_relu(x @ W + b); f = h; g = h * dinv[row]
__global__ __launch_bounds__(256) void gemm_kernel(const float* __restrict__ x,
                                                   const float* __restrict__ W,
                                                   const float* __restrict__ b,
                                                   const float* __restrict__ dinv,
                                                   float* __restrict__ f,
                                                   float* __restrict__ g) {
    __shared__ __align__(16) float xs[64][33];
    __shared__ __align__(16) float ws[32][64];
    int tid = threadIdx.x;
    int row0 = blockIdx.x * 64;
    int tc = (tid & 15) * 4;
    int tr = (tid >> 4) * 4;
    float acc[4][4] = {};
    for (int kb = 0; kb < INF; kb += 32) {
        for (int l = tid; l < 512; l += 256) {
            int r  = l >> 3;
            int kq = (l & 7) * 4;
            float4 v = make_float4(0.f, 0.f, 0.f, 0.f);
            int grow = row0 + r;
            if (grow < NN) v = *(const float4*)&x[(size_t)grow * INF + kb + kq];
            xs[r][kq + 0] = v.x; xs[r][kq + 1] = v.y; xs[r][kq + 2] = v.z; xs[r][kq + 3] = v.w;
        }
        for (int l = tid; l < 512; l += 256) {
            float4 v = *(const float4*)&W[kb * HF + l * 4];
            int kk = (l * 4) >> 6;
            int cc = (l * 4) & 63;
            ws[kk][cc + 0] = v.x; ws[kk][cc + 1] = v.y; ws[kk][cc + 2] = v.z; ws[kk][cc + 3] = v.w;
        }
        __syncthreads();
        #pragma unroll 8
        for (int k = 0; k < 32; ++k) {
            float4 wq = *(const float4*)&ws[k][tc];
            #pragma unroll
            for (int i = 0; i < 4; ++i) {
                float xv = xs[tr + i][k];
                acc[i][0] += xv * wq.x;
                acc[i][1] += xv * wq.y;
                acc[i][2] += xv * wq.z;
                acc[i][3] += xv * wq.w;
            }
        }
        __syncthreads();
    }
    #pragma unroll
    for (int i = 0; i < 4; ++i) {
        int row = row0 + tr + i;
        if (row < NN) {
            float dv = dinv[row];
            #pragma unroll
            for (int jj = 0; jj < 4; ++jj) {
                int c = tc + jj;
                float h = acc[i][jj] + b[c];
                h = (h > 0.f) ? h : 0.01f * h;
                f[(size_t)row * HF + c] = h;
                g[(size_t)row * HF + c] = h * dv;
            }
        }
    }
}

// one wave per node; lane = feature. msg = sum_{j in row} g_in[col[j]];
// f_new = f_in - msg*dinv; write f_new to f_out (slot or buffer); g_out = f_new*dinv
__global__ __launch_bounds__(256) void prop_kernel(const int* __restrict__ row_ptr,
                                                   const int* __restrict__ col,
                                                   const float* __restrict__ dinv,
                                                   const float* __restrict__ g_in,
                                                   const float* __restrict__ f_in, int fin_stride,
                                                   float* __restrict__ f_out, int fout_stride,
                                                   float* __restrict__ g_out) {
    int wid = (blockIdx.x * 256 + threadIdx.x) >> 6;   // node
    int c = threadIdx.x & 63;                          // feature
    if (wid >= NN) return;
    int start = row_ptr[wid];
    int end   = row_ptr[wid + 1];
    float s = 0.f;
    int j = start;
    for (; j + 4 <= end; j += 4) {
        int c0 = col[j + 0] * HF;
        int c1 = col[j + 1] * HF;
        int c2 = col[j + 2] * HF;
        int c3 = col[j + 3] * HF;
        float a0 = g_in[c0 + c];
        float a1 = g_in[c1 + c];
        float a2 = g_in[c2 + c];
        float a3 = g_in[c3 + c];
        s += (a0 + a1) + (a2 + a3);
    }
    for (; j < end; ++j) s += g_in[col[j] * HF + c];
    float dv = dinv[wid];
    float fv = f_in[(size_t)wid * fin_stride + c] - s * dv;
    f_out[(size_t)wid * fout_stride + c] = fv;
    if (g_out) g_out[wid * HF + c] = fv * dv;
}

// out slot t currently holds f_{t+2}; apply upper-triangular theta combo in place
__global__ __launch_bounds__(256) void final_kernel(float* __restrict__ out, ThetaM tm) {
    int idx = blockIdx.x * 256 + threadIdx.x;          // over NN*64
    if (idx >= NN * HF) return;
    int n = idx >> 6;
    int c = idx & 63;
    float v[5];
    #pragma unroll
    for (int j = 0; j < 5; ++j) v[j] = out[(size_t)n * OUTF + j * HF + c];
    #pragma unroll
    for (int t = 0; t < 5; ++t) {
        float o = 0.f;
        #pragma unroll
        for (int j = 0; j < 5; ++j) {
            if (j >= t) o += tm.m[t][j + 2] * v[j];    // k = j+2
        }
        out[(size_t)n * OUTF + t * HF + c] = o;
    }
}

// ---------------- launch -----------------------------------------------------
extern "C" void kernel_launch(void* const* d_in, const int* in_sizes, int n_in,
                              void* d_out, int out_size, void* d_ws, size_t ws_size,
                              hipStream_t stream) {
    const float* x  = (const float*)d_in[0];
    const float* W  = (const float*)d_in[1];
    const float* b  = (const float*)d_in[2];
    const int* src  = (const int*)d_in[3];
    const int* dst  = (const int*)d_in[4];
    float* out = (float*)d_out;

    char* ws = (char*)d_ws;
    size_t off = 0;
    auto alloc = [&](size_t bytes) -> void* {
        void* p = ws + off;
        off += (bytes + 255) & ~(size_t)255;
        return p;
    };
    int*   cnt_src = (int*)alloc((size_t)NN * 4);
    int*   cnt_dst = (int*)alloc((size_t)NN * 4);
    int*   row_ptr = (int*)alloc((size_t)(NN + 1) * 4);
    int*   cursor  = (int*)alloc((size_t)NN * 4);
    int*   partial = (int*)alloc((size_t)NB * 4);
    int*   offsets = (int*)alloc((size_t)NB * 4);
    float* dinv    = (float*)alloc((size_t)NN * 4);
    int*   col     = (int*)alloc((size_t)NE * 4);
    float* fbuf    = (float*)alloc((size_t)NN * HF * 4);
    float* gA      = (float*)alloc((size_t)NN * HF * 4);
    float* gB      = (float*)alloc((size_t)NN * HF * 4);

    hipMemsetAsync(cnt_src, 0, (size_t)NN * 4, stream);
    hipMemsetAsync(cnt_dst, 0, (size_t)NN * 4, stream);

    count_kernel<<<(NE + 255) / 256, 256, 0, stream>>>(src, dst, cnt_src, cnt_dst);
    dinv_kernel<<<NB, 256, 0, stream>>>(cnt_src, dinv);
    scan_reduce_kernel<<<NB, 256, 0, stream>>>(cnt_dst, partial);
    scan_partials_kernel<<<1, 256, 0, stream>>>(partial, offsets, row_ptr);
    scan_write_kernel<<<NB, 256, 0, stream>>>(cnt_dst, offsets, row_ptr, cursor);
    fill_kernel<<<(NE + 255) / 256, 256, 0, stream>>>(src, dst, cursor, col);
    gemm_kernel<<<(NN + 63) / 64, 256, 0, stream>>>(x, W, b, dinv, fbuf, gA);

    const int PB = (NN * HF + 255) / 256;
    // k=1: f stays in fbuf; g: gA -> gB
    prop_kernel<<<PB, 256, 0, stream>>>(row_ptr, col, dinv, gA, fbuf, HF, fbuf, HF, gB);
    // k=2: f: fbuf -> slot0; g: gB -> gA
    prop_kernel<<<PB, 256, 0, stream>>>(row_ptr, col, dinv, gB, fbuf, HF, out + 0 * HF, OUTF, gA);
    // k=3: slot0 -> slot1; g: gA -> gB
    prop_kernel<<<PB, 256, 0, stream>>>(row_ptr, col, dinv, gA, out + 0 * HF, OUTF, out + 1 * HF, OUTF, gB);
    // k=4: slot1 -> slot2; g: gB -> gA
    prop_kernel<<<PB, 256, 0, stream>>>(row_ptr, col, dinv, gB, out + 1 * HF, OUTF, out + 2 * HF, OUTF, gA);
    // k=5: slot2 -> slot3; g: gA -> gB
    prop_kernel<<<PB, 256, 0, stream>>>(row_ptr, col, dinv, gA, out + 2 * HF, OUTF, out + 3 * HF, OUTF, gB);
    // k=6: slot3 -> slot4; g unused
    prop_kernel<<<PB, 256, 0, stream>>>(row_ptr, col, dinv, gB, out + 3 * HF, OUTF, out + 4 * HF, OUTF, nullptr);

    ThetaM tm;
    compute_theta(tm);
    final_kernel<<<PB, 256, 0, stream>>>(out, tm);
}

// Round 3
// 448.089 us; speedup vs baseline: 1.3998x; 1.1244x over previous
//
#include <hip/hip_runtime.h>
#include <math.h>

#define NN 50000
#define NNH 25000          // NN/2 packed u32 bins
#define NE 800000
#define INF 256
#define HF 64
#define OUTF 320           // 5 * 64
#define NB ((NN + 255) / 256)   // 196 blocks for node-range kernels
#define G 64               // histogram slices per index array
#define SL (NE / G)        // 12500 edges per slice

// ---------------- theta (computed on host each launch) ----------------------
struct ThetaM { float m[5][7]; };

static void compute_theta(ThetaM& tm) {
    const double e = 1.4;
    auto fact = [](int n) { double r = 1.0; for (int i = 2; i <= n; ++i) r *= i; return r; };
    for (int t = 0; t < 5; ++t) {
        int i = t + 2;              // i in [2,6]
        int mm = 6 - i;             // d - i + OFFSET
        double B = fact(i) * fact(6 - i) / fact(7);   // beta(i+1, 7-i)
        for (int k = 0; k < 7; ++k) tm.m[t][k] = 0.f;
        for (int j = 0; j <= mm; ++j) {
            double cb = fact(mm) / (fact(j) * fact(mm - j));
            double v = pow(1.0 / e, (double)i) * cb * pow(-1.0 / e, (double)j) / (e * B);
            tm.m[t][i + j] = (float)v;
        }
    }
}

// ---------------- histogram stage (no global atomics) -----------------------
// grid 2G: blocks [0,G) histogram dst slices, [G,2G) histogram src slices.
// Two u16 counts packed per u32 LDS bin; per-slice count <= SL < 65536.
__global__ __launch_bounds__(1024) void hist_kernel(const int* __restrict__ src,
                                                    const int* __restrict__ dst,
                                                    unsigned short* __restrict__ hist_src,
                                                    unsigned short* __restrict__ hist_dst) {
    __shared__ unsigned int h[NNH];
    int b = blockIdx.x;
    const int* arr = (b < G) ? dst : src;
    unsigned short* outp = (b < G) ? hist_dst : hist_src;
    int bb = (b < G) ? b : b - G;
    for (int i = threadIdx.x; i < NNH; i += 1024) h[i] = 0u;
    __syncthreads();
    int base = bb * SL;
    for (int i = threadIdx.x; i < SL; i += 1024) {
        int d = arr[base + i];
        atomicAdd(&h[d >> 1], 1u << ((d & 1) * 16));
    }
    __syncthreads();
    unsigned int* out32 = (unsigned int*)(outp + (size_t)bb * NN);
    for (int i = threadIdx.x; i < NNH; i += 1024) out32[i] = h[i];
}

// merge dst histograms: per node, exclusive scan over blocks (in place) + total
__global__ __launch_bounds__(256) void merge_dst_kernel(unsigned short* __restrict__ hist,
                                                        int* __restrict__ cnt) {
    int d = blockIdx.x * 256 + threadIdx.x;
    if (d >= NN) return;
    int run = 0;
    for (int b = 0; b < G; ++b) {
        size_t idx = (size_t)b * NN + d;
        int v = hist[idx];
        hist[idx] = (unsigned short)run;   // exclusive per-block offset
        run += v;
    }
    cnt[d] = run;
}

// merge src histograms: total degree -> dinv directly
__global__ __launch_bounds__(256) void merge_src_kernel(const unsigned short* __restrict__ hist,
                                                        float* __restrict__ dinv) {
    int d = blockIdx.x * 256 + threadIdx.x;
    if (d >= NN) return;
    int run = 0;
    for (int b = 0; b < G; ++b) run += hist[(size_t)b * NN + d];
    float dd = (float)run;
    if (dd < 1.f) dd = 1.f;
    dinv[d] = 1.0f / sqrtf(dd);
}

// ---- multi-block exclusive scan of cnt_dst -> row_ptr ----------------------
__global__ __launch_bounds__(256) void scan_reduce_kernel(const int* __restrict__ cnt,
                                                          int* __restrict__ partial) {
    __shared__ int s[256];
    int tid = threadIdx.x;
    int gid = blockIdx.x * 256 + tid;
    s[tid] = (gid < NN) ? cnt[gid] : 0;
    __syncthreads();
    for (int off = 128; off > 0; off >>= 1) {
        if (tid < off) s[tid] += s[tid + off];
        __syncthreads();
    }
    if (tid == 0) partial[blockIdx.x] = s[0];
}

__global__ __launch_bounds__(256) void scan_partials_kernel(const int* __restrict__ partial,
                                                            int* __restrict__ offsets,
                                                            int* __restrict__ row_ptr) {
    __shared__ int s[256];
    int tid = threadIdx.x;
    s[tid] = (tid < NB) ? partial[tid] : 0;
    __syncthreads();
    for (int off = 1; off < 256; off <<= 1) {
        int t = (tid >= off) ? s[tid - off] : 0;
        __syncthreads();
        s[tid] += t;
        __syncthreads();
    }
    if (tid < NB) offsets[tid] = (tid == 0) ? 0 : s[tid - 1];
    if (tid == 0) row_ptr[NN] = NE;
}

__global__ __launch_bounds__(256) void scan_write_kernel(const int* __restrict__ cnt,
                                                         const int* __restrict__ offsets,
                                                         int* __restrict__ row_ptr) {
    __shared__ int s[256];
    int tid = threadIdx.x;
    int gid = blockIdx.x * 256 + tid;
    int c = (gid < NN) ? cnt[gid] : 0;
    s[tid] = c;
    __syncthreads();
    for (int off = 1; off < 256; off <<= 1) {
        int t = (tid >= off) ? s[tid - off] : 0;
        __syncthreads();
        s[tid] += t;
        __syncthreads();
    }
    if (gid < NN) row_ptr[gid] = offsets[blockIdx.x] + s[tid] - c;  // exclusive
}

// ---- fill: deterministic placement, LDS-rank only, no global atomics -------
__global__ __launch_bounds__(1024) void fill_kernel(const int* __restrict__ src,
                                                    const int* __restrict__ dst,
                                                    const unsigned short* __restrict__ hist_dst,
                                                    const int* __restrict__ row_ptr,
                                                    int* __restrict__ col) {
    __shared__ unsigned int cur[NNH];
    int b = blockIdx.x;
    for (int i = threadIdx.x; i < NNH; i += 1024) cur[i] = 0u;
    __syncthreads();
    int base = b * SL;
    const unsigned short* hrow = hist_dst + (size_t)b * NN;
    for (int i = threadIdx.x; i < SL; i += 1024) {
        int d = dst[base + i];
        int sh = (d & 1) * 16;
        unsigned int old = atomicAdd(&cur[d >> 1], 1u << sh);
        int rank = (int)((old >> sh) & 0xFFFFu);
        int pos = row_ptr[d] + (int)hrow[d] + rank;
        col[pos] = src[base + i];
    }
}

// h = leaky_relu(x @ W + b); f = h; g = h * dinv[row]
__global__ __launch_bounds__(256) void gemm_kernel(const float* __restrict__ x,
                                                   const float* __restrict__ W,
                                                   const float* __restrict__ b,
                                                   const float* __restrict__ dinv,
                                                   float* __restrict__ f,
                                                   float* __restrict__ g) {
    __shared__ __align__(16) float xs[64][33];
    __shared__ __align__(16) float ws[32][64];
    int tid = threadIdx.x;
    int row0 = blockIdx.x * 64;
    int tc = (tid & 15) * 4;
    int tr = (tid >> 4) * 4;
    float acc[4][4] = {};
    for (int kb = 0; kb < INF; kb += 32) {
        for (int l = tid; l < 512; l += 256) {
            int r  = l >> 3;
            int kq = (l & 7) * 4;
            float4 v = make_float4(0.f, 0.f, 0.f, 0.f);
            int grow = row0 + r;
            if (grow < NN) v = *(const float4*)&x[(size_t)grow * INF + kb + kq];
            xs[r][kq + 0] = v.x; xs[r][kq + 1] = v.y; xs[r][kq + 2] = v.z; xs[r][kq + 3] = v.w;
        }
        for (int l = tid; l < 512; l += 256) {
            float4 v = *(const float4*)&W[kb * HF + l * 4];
            int kk = (l * 4) >> 6;
            int cc = (l * 4) & 63;
            ws[kk][cc + 0] = v.x; ws[kk][cc + 1] = v.y; ws[kk][cc + 2] = v.z; ws[kk][cc + 3] = v.w;
        }
        __syncthreads();
        #pragma unroll 8
        for (int k = 0; k < 32; ++k) {
            float4 wq = *(const float4*)&ws[k][tc];
            #pragma unroll
            for (int i = 0; i < 4; ++i) {
                float xv = xs[tr + i][k];
                acc[i][0] += xv * wq.x;
                acc[i][1] += xv * wq.y;
                acc[i][2] += xv * wq.z;
                acc[i][3] += xv * wq.w;
            }
        }
        __syncthreads();
    }
    #pragma unroll
    for (int i = 0; i < 4; ++i) {
        int row = row0 + tr + i;
        if (row < NN) {
            float dv = dinv[row];
            #pragma unroll
            for (int jj = 0; jj < 4; ++jj) {
                int c = tc + jj;
                float h = acc[i][jj] + b[c];
                h = (h > 0.f) ? h : 0.01f * h;
                f[(size_t)row * HF + c] = h;
                g[(size_t)row * HF + c] = h * dv;
            }
        }
    }
}

// one wave per node; lane = feature. msg = sum_{j in row} g_in[col[j]];
// f_new = f_in - msg*dinv; write f_new to f_out; g_out = f_new*dinv
__global__ __launch_bounds__(256) void prop_kernel(const int* __restrict__ row_ptr,
                                                   const int* __restrict__ col,
                                                   const float* __restrict__ dinv,
                                                   const float* __restrict__ g_in,
                                                   const float* __restrict__ f_in, int fin_stride,
                                                   float* __restrict__ f_out, int fout_stride,
                                                   float* __restrict__ g_out) {
    int wid = (blockIdx.x * 256 + threadIdx.x) >> 6;   // node
    int c = threadIdx.x & 63;                          // feature
    if (wid >= NN) return;
    int start = row_ptr[wid];
    int end   = row_ptr[wid + 1];
    float s = 0.f;
    int j = start;
    for (; j + 8 <= end; j += 8) {
        int o0 = col[j + 0] * HF; int o1 = col[j + 1] * HF;
        int o2 = col[j + 2] * HF; int o3 = col[j + 3] * HF;
        int o4 = col[j + 4] * HF; int o5 = col[j + 5] * HF;
        int o6 = col[j + 6] * HF; int o7 = col[j + 7] * HF;
        float a0 = g_in[o0 + c]; float a1 = g_in[o1 + c];
        float a2 = g_in[o2 + c]; float a3 = g_in[o3 + c];
        float a4 = g_in[o4 + c]; float a5 = g_in[o5 + c];
        float a6 = g_in[o6 + c]; float a7 = g_in[o7 + c];
        s += ((a0 + a1) + (a2 + a3)) + ((a4 + a5) + (a6 + a7));
    }
    for (; j < end; ++j) s += g_in[col[j] * HF + c];
    float dv = dinv[wid];
    float fv = f_in[(size_t)wid * fin_stride + c] - s * dv;
    f_out[(size_t)wid * fout_stride + c] = fv;
    if (g_out) g_out[wid * HF + c] = fv * dv;
}

// out slot t currently holds f_{t+2}; apply upper-triangular theta combo in place
__global__ __launch_bounds__(256) void final_kernel(float* __restrict__ out, ThetaM tm) {
    int idx = blockIdx.x * 256 + threadIdx.x;          // over NN*64
    if (idx >= NN * HF) return;
    int n = idx >> 6;
    int c = idx & 63;
    float v[5];
    #pragma unroll
    for (int j = 0; j < 5; ++j) v[j] = out[(size_t)n * OUTF + j * HF + c];
    #pragma unroll
    for (int t = 0; t < 5; ++t) {
        float o = 0.f;
        #pragma unroll
        for (int j = 0; j < 5; ++j) {
            if (j >= t) o += tm.m[t][j + 2] * v[j];    // k = j+2
        }
        out[(size_t)n * OUTF + t * HF + c] = o;
    }
}

// ---------------- launch -----------------------------------------------------
extern "C" void kernel_launch(void* const* d_in, const int* in_sizes, int n_in,
                              void* d_out, int out_size, void* d_ws, size_t ws_size,
                              hipStream_t stream) {
    const float* x  = (const float*)d_in[0];
    const float* W  = (const float*)d_in[1];
    const float* b  = (const float*)d_in[2];
    const int* src  = (const int*)d_in[3];
    const int* dst  = (const int*)d_in[4];
    float* out = (float*)d_out;

    char* ws = (char*)d_ws;
    size_t off = 0;
    auto alloc = [&](size_t bytes) -> void* {
        void* p = ws + off;
        off += (bytes + 255) & ~(size_t)255;
        return p;
    };
    unsigned short* hist_dst = (unsigned short*)alloc((size_t)G * NN * 2);
    unsigned short* hist_src = (unsigned short*)alloc((size_t)G * NN * 2);
    int*   cnt_dst = (int*)alloc((size_t)NN * 4);
    int*   row_ptr = (int*)alloc((size_t)(NN + 1) * 4);
    int*   partial = (int*)alloc((size_t)NB * 4);
    int*   offsets = (int*)alloc((size_t)NB * 4);
    float* dinv    = (float*)alloc((size_t)NN * 4);
    int*   col     = (int*)alloc((size_t)NE * 4);
    float* fbuf    = (float*)alloc((size_t)NN * HF * 4);
    float* gA      = (float*)alloc((size_t)NN * HF * 4);
    float* gB      = (float*)alloc((size_t)NN * HF * 4);

    hist_kernel<<<2 * G, 1024, 0, stream>>>(src, dst, hist_src, hist_dst);
    merge_dst_kernel<<<NB, 256, 0, stream>>>(hist_dst, cnt_dst);
    merge_src_kernel<<<NB, 256, 0, stream>>>(hist_src, dinv);
    scan_reduce_kernel<<<NB, 256, 0, stream>>>(cnt_dst, partial);
    scan_partials_kernel<<<1, 256, 0, stream>>>(partial, offsets, row_ptr);
    scan_write_kernel<<<NB, 256, 0, stream>>>(cnt_dst, offsets, row_ptr);
    fill_kernel<<<G, 1024, 0, stream>>>(src, dst, hist_dst, row_ptr, col);
    gemm_kernel<<<(NN + 63) / 64, 256, 0, stream>>>(x, W, b, dinv, fbuf, gA);

    const int PB = (NN * HF + 255) / 256;
    // k=1: f stays in fbuf; g: gA -> gB
    prop_kernel<<<PB, 256, 0, stream>>>(row_ptr, col, dinv, gA, fbuf, HF, fbuf, HF, gB);
    // k=2: f: fbuf -> slot0; g: gB -> gA
    prop_kernel<<<PB, 256, 0, stream>>>(row_ptr, col, dinv, gB, fbuf, HF, out + 0 * HF, OUTF, gA);
    // k=3: slot0 -> slot1; g: gA -> gB
    prop_kernel<<<PB, 256, 0, stream>>>(row_ptr, col, dinv, gA, out + 0 * HF, OUTF, out + 1 * HF, OUTF, gB);
    // k=4: slot1 -> slot2; g: gB -> gA
    prop_kernel<<<PB, 256, 0, stream>>>(row_ptr, col, dinv, gB, out + 1 * HF, OUTF, out + 2 * HF, OUTF, gA);
    // k=5: slot2 -> slot3; g: gA -> gB
    prop_kernel<<<PB, 256, 0, stream>>>(row_ptr, col, dinv, gA, out + 2 * HF, OUTF, out + 3 * HF, OUTF, gB);
    // k=6: slot3 -> slot4; g unused
    prop_kernel<<<PB, 256, 0, stream>>>(row_ptr, col, dinv, gB, out + 3 * HF, OUTF, out + 4 * HF, OUTF, nullptr);

    ThetaM tm;
    compute_theta(tm);
    final_kernel<<<PB, 256, 0, stream>>>(out, tm);
}

// Round 5
// 434.364 us; speedup vs baseline: 1.4441x; 1.0316x over previous
//
#include <hip/hip_runtime.h>
#include <math.h>

#define NN 50000
#define NNH 25000          // NN/2 packed u32 bins
#define NE 800000
#define INF 256
#define HF 64
#define OUTF 320           // 5 * 64
#define NB ((NN + 255) / 256)   // 196 blocks for node-range kernels
#define G 64               // histogram slices per index array
#define SL (NE / G)        // 12500 edges per slice

// ---------------- fp16 helpers (10 mantissa bits; 8x lower ulp than bf16) ---
static __device__ __forceinline__ unsigned short f2h(float x) {
    _Float16 h = (_Float16)x;                 // v_cvt_f16_f32, RNE
    return *(unsigned short*)&h;
}
static __device__ __forceinline__ float h2f(unsigned short u) {
    _Float16 h = *(_Float16*)&u;
    return (float)h;                          // v_cvt_f32_f16
}

// ---------------- theta (computed on host each launch) ----------------------
struct ThetaM { float m[5][7]; };

static void compute_theta(ThetaM& tm) {
    const double e = 1.4;
    auto fact = [](int n) { double r = 1.0; for (int i = 2; i <= n; ++i) r *= i; return r; };
    for (int t = 0; t < 5; ++t) {
        int i = t + 2;              // i in [2,6]
        int mm = 6 - i;             // d - i + OFFSET
        double B = fact(i) * fact(6 - i) / fact(7);   // beta(i+1, 7-i)
        for (int k = 0; k < 7; ++k) tm.m[t][k] = 0.f;
        for (int j = 0; j <= mm; ++j) {
            double cb = fact(mm) / (fact(j) * fact(mm - j));
            double v = pow(1.0 / e, (double)i) * cb * pow(-1.0 / e, (double)j) / (e * B);
            tm.m[t][i + j] = (float)v;
        }
    }
}

// ---------------- histogram stage (no global atomics) -----------------------
__global__ __launch_bounds__(1024) void hist_kernel(const int* __restrict__ src,
                                                    const int* __restrict__ dst,
                                                    unsigned short* __restrict__ hist_src,
                                                    unsigned short* __restrict__ hist_dst) {
    __shared__ unsigned int h[NNH];
    int b = blockIdx.x;
    const int* arr = (b < G) ? dst : src;
    unsigned short* outp = (b < G) ? hist_dst : hist_src;
    int bb = (b < G) ? b : b - G;
    for (int i = threadIdx.x; i < NNH; i += 1024) h[i] = 0u;
    __syncthreads();
    int base = bb * SL;
    for (int i = threadIdx.x; i < SL; i += 1024) {
        int d = arr[base + i];
        atomicAdd(&h[d >> 1], 1u << ((d & 1) * 16));
    }
    __syncthreads();
    unsigned int* out32 = (unsigned int*)(outp + (size_t)bb * NN);
    for (int i = threadIdx.x; i < NNH; i += 1024) out32[i] = h[i];
}

// merge dst histograms: per node exclusive scan over blocks (in place), total
// count, and fused per-block partial sum for the global scan.
__global__ __launch_bounds__(256) void merge_dst_kernel(unsigned short* __restrict__ hist,
                                                        int* __restrict__ cnt,
                                                        int* __restrict__ partial) {
    __shared__ int s[256];
    int tid = threadIdx.x;
    int d = blockIdx.x * 256 + tid;
    int run = 0;
    if (d < NN) {
        for (int b = 0; b < G; ++b) {
            size_t idx = (size_t)b * NN + d;
            int v = hist[idx];
            hist[idx] = (unsigned short)run;   // exclusive per-block offset
            run += v;
        }
        cnt[d] = run;
    }
    s[tid] = run;
    __syncthreads();
    for (int off = 128; off > 0; off >>= 1) {
        if (tid < off) s[tid] += s[tid + off];
        __syncthreads();
    }
    if (tid == 0) partial[blockIdx.x] = s[0];
}

// merge src histograms: total degree -> dinv directly
__global__ __launch_bounds__(256) void merge_src_kernel(const unsigned short* __restrict__ hist,
                                                        float* __restrict__ dinv) {
    int d = blockIdx.x * 256 + threadIdx.x;
    if (d >= NN) return;
    int run = 0;
    for (int b = 0; b < G; ++b) run += hist[(size_t)b * NN + d];
    float dd = (float)run;
    if (dd < 1.f) dd = 1.f;
    dinv[d] = 1.0f / sqrtf(dd);
}

__global__ __launch_bounds__(256) void scan_partials_kernel(const int* __restrict__ partial,
                                                            int* __restrict__ offsets,
                                                            int* __restrict__ row_ptr) {
    __shared__ int s[256];
    int tid = threadIdx.x;
    s[tid] = (tid < NB) ? partial[tid] : 0;
    __syncthreads();
    for (int off = 1; off < 256; off <<= 1) {
        int t = (tid >= off) ? s[tid - off] : 0;
        __syncthreads();
        s[tid] += t;
        __syncthreads();
    }
    if (tid < NB) offsets[tid] = (tid == 0) ? 0 : s[tid - 1];
    if (tid == 0) row_ptr[NN] = NE;
}

__global__ __launch_bounds__(256) void scan_write_kernel(const int* __restrict__ cnt,
                                                         const int* __restrict__ offsets,
                                                         int* __restrict__ row_ptr) {
    __shared__ int s[256];
    int tid = threadIdx.x;
    int gid = blockIdx.x * 256 + tid;
    int c = (gid < NN) ? cnt[gid] : 0;
    s[tid] = c;
    __syncthreads();
    for (int off = 1; off < 256; off <<= 1) {
        int t = (tid >= off) ? s[tid - off] : 0;
        __syncthreads();
        s[tid] += t;
        __syncthreads();
    }
    if (gid < NN) row_ptr[gid] = offsets[blockIdx.x] + s[tid] - c;  // exclusive
}

// ---- fill: deterministic placement, LDS-rank only, no global atomics -------
__global__ __launch_bounds__(1024) void fill_kernel(const int* __restrict__ src,
                                                    const int* __restrict__ dst,
                                                    const unsigned short* __restrict__ hist_dst,
                                                    const int* __restrict__ row_ptr,
                                                    int* __restrict__ col) {
    __shared__ unsigned int cur[NNH];
    int b = blockIdx.x;
    for (int i = threadIdx.x; i < NNH; i += 1024) cur[i] = 0u;
    __syncthreads();
    int base = b * SL;
    const unsigned short* hrow = hist_dst + (size_t)b * NN;
    for (int i = threadIdx.x; i < SL; i += 1024) {
        int d = dst[base + i];
        int sh = (d & 1) * 16;
        unsigned int old = atomicAdd(&cur[d >> 1], 1u << sh);
        int rank = (int)((old >> sh) & 0xFFFFu);
        int pos = row_ptr[d] + (int)hrow[d] + rank;
        col[pos] = src[base + i];
    }
}

// h = leaky_relu(x @ W + b); f = h (fp32); g = fp16(h * dinv[row])
// 64-row tile, 4x4 thread tile, all-float4 LDS reads (k step of 4)
__global__ __launch_bounds__(256) void gemm_kernel(const float* __restrict__ x,
                                                   const float* __restrict__ W,
                                                   const float* __restrict__ b,
                                                   const float* __restrict__ dinv,
                                                   float* __restrict__ f,
                                                   unsigned short* __restrict__ g) {
    __shared__ __align__(16) float xs[64][36];   // pad 4 -> rows 144B (16B aligned)
    __shared__ __align__(16) float ws[32][64];
    int tid = threadIdx.x;
    int row0 = blockIdx.x * 64;
    int tc = (tid & 15) * 4;
    int tr = (tid >> 4) * 4;
    float acc[4][4] = {};
    for (int kb = 0; kb < INF; kb += 32) {
        for (int l = tid; l < 512; l += 256) {
            int r  = l >> 3;
            int kq = (l & 7) * 4;
            float4 v = make_float4(0.f, 0.f, 0.f, 0.f);
            int grow = row0 + r;
            if (grow < NN) v = *(const float4*)&x[(size_t)grow * INF + kb + kq];
            *(float4*)&xs[r][kq] = v;
        }
        for (int l = tid; l < 512; l += 256) {
            float4 v = *(const float4*)&W[kb * HF + l * 4];
            int kk = (l * 4) >> 6;
            int cc = (l * 4) & 63;
            *(float4*)&ws[kk][cc] = v;
        }
        __syncthreads();
        #pragma unroll
        for (int k4 = 0; k4 < 8; ++k4) {
            float4 xa[4], wb[4];
            #pragma unroll
            for (int i = 0; i < 4; ++i) xa[i] = *(const float4*)&xs[tr + i][k4 * 4];
            #pragma unroll
            for (int j = 0; j < 4; ++j) wb[j] = *(const float4*)&ws[k4 * 4 + j][tc];
            #pragma unroll
            for (int i = 0; i < 4; ++i) {
                acc[i][0] += xa[i].x * wb[0].x + xa[i].y * wb[1].x + xa[i].z * wb[2].x + xa[i].w * wb[3].x;
                acc[i][1] += xa[i].x * wb[0].y + xa[i].y * wb[1].y + xa[i].z * wb[2].y + xa[i].w * wb[3].y;
                acc[i][2] += xa[i].x * wb[0].z + xa[i].y * wb[1].z + xa[i].z * wb[2].z + xa[i].w * wb[3].z;
                acc[i][3] += xa[i].x * wb[0].w + xa[i].y * wb[1].w + xa[i].z * wb[2].w + xa[i].w * wb[3].w;
            }
        }
        __syncthreads();
    }
    #pragma unroll
    for (int i = 0; i < 4; ++i) {
        int row = row0 + tr + i;
        if (row < NN) {
            float dv = dinv[row];
            float hv[4];
            #pragma unroll
            for (int jj = 0; jj < 4; ++jj) {
                float h = acc[i][jj] + b[tc + jj];
                hv[jj] = (h > 0.f) ? h : 0.01f * h;
            }
            *(float4*)&f[(size_t)row * HF + tc] = make_float4(hv[0], hv[1], hv[2], hv[3]);
            ushort4 gv;
            gv.x = f2h(hv[0] * dv); gv.y = f2h(hv[1] * dv);
            gv.z = f2h(hv[2] * dv); gv.w = f2h(hv[3] * dv);
            *(ushort4*)&g[(size_t)row * HF + tc] = gv;
        }
    }
}

// one wave per node; lane = feature. msg = sum_{j in row} fp16 g_in[col[j]];
// f_new = f_in - msg*dinv; f_out fp32; g_out fp16
__global__ __launch_bounds__(256) void prop_kernel(const int* __restrict__ row_ptr,
                                                   const int* __restrict__ col,
                                                   const float* __restrict__ dinv,
                                                   const unsigned short* __restrict__ g_in,
                                                   const float* __restrict__ f_in, int fin_stride,
                                                   float* __restrict__ f_out, int fout_stride,
                                                   unsigned short* __restrict__ g_out) {
    int wid = (blockIdx.x * 256 + threadIdx.x) >> 6;   // node
    int c = threadIdx.x & 63;                          // feature
    if (wid >= NN) return;
    int start = row_ptr[wid];
    int end   = row_ptr[wid + 1];
    float s = 0.f;
    int j = start;
    for (; j + 8 <= end; j += 8) {
        int o0 = col[j + 0] * HF; int o1 = col[j + 1] * HF;
        int o2 = col[j + 2] * HF; int o3 = col[j + 3] * HF;
        int o4 = col[j + 4] * HF; int o5 = col[j + 5] * HF;
        int o6 = col[j + 6] * HF; int o7 = col[j + 7] * HF;
        float a0 = h2f(g_in[o0 + c]); float a1 = h2f(g_in[o1 + c]);
        float a2 = h2f(g_in[o2 + c]); float a3 = h2f(g_in[o3 + c]);
        float a4 = h2f(g_in[o4 + c]); float a5 = h2f(g_in[o5 + c]);
        float a6 = h2f(g_in[o6 + c]); float a7 = h2f(g_in[o7 + c]);
        s += ((a0 + a1) + (a2 + a3)) + ((a4 + a5) + (a6 + a7));
    }
    for (; j < end; ++j) s += h2f(g_in[col[j] * HF + c]);
    float dv = dinv[wid];
    float fv = f_in[(size_t)wid * fin_stride + c] - s * dv;
    f_out[(size_t)wid * fout_stride + c] = fv;
    if (g_out) g_out[wid * HF + c] = f2h(fv * dv);
}

// out slot t currently holds f_{t+2}; apply upper-triangular theta combo in place
__global__ __launch_bounds__(256) void final_kernel(float* __restrict__ out, ThetaM tm) {
    int idx = blockIdx.x * 256 + threadIdx.x;          // over NN*64
    if (idx >= NN * HF) return;
    int n = idx >> 6;
    int c = idx & 63;
    float v[5];
    #pragma unroll
    for (int j = 0; j < 5; ++j) v[j] = out[(size_t)n * OUTF + j * HF + c];
    #pragma unroll
    for (int t = 0; t < 5; ++t) {
        float o = 0.f;
        #pragma unroll
        for (int j = 0; j < 5; ++j) {
            if (j >= t) o += tm.m[t][j + 2] * v[j];    // k = j+2
        }
        out[(size_t)n * OUTF + t * HF + c] = o;
    }
}

// ---------------- launch -----------------------------------------------------
extern "C" void kernel_launch(void* const* d_in, const int* in_sizes, int n_in,
                              void* d_out, int out_size, void* d_ws, size_t ws_size,
                              hipStream_t stream) {
    const float* x  = (const float*)d_in[0];
    const float* W  = (const float*)d_in[1];
    const float* b  = (const float*)d_in[2];
    const int* src  = (const int*)d_in[3];
    const int* dst  = (const int*)d_in[4];
    float* out = (float*)d_out;

    char* ws = (char*)d_ws;
    size_t off = 0;
    auto alloc = [&](size_t bytes) -> void* {
        void* p = ws + off;
        off += (bytes + 255) & ~(size_t)255;
        return p;
    };
    unsigned short* hist_dst = (unsigned short*)alloc((size_t)G * NN * 2);
    unsigned short* hist_src = (unsigned short*)alloc((size_t)G * NN * 2);
    int*   cnt_dst = (int*)alloc((size_t)NN * 4);
    int*   row_ptr = (int*)alloc((size_t)(NN + 1) * 4);
    int*   partial = (int*)alloc((size_t)NB * 4);
    int*   offsets = (int*)alloc((size_t)NB * 4);
    float* dinv    = (float*)alloc((size_t)NN * 4);
    int*   col     = (int*)alloc((size_t)NE * 4);
    float* fbuf    = (float*)alloc((size_t)NN * HF * 4);
    unsigned short* gA = (unsigned short*)alloc((size_t)NN * HF * 2);
    unsigned short* gB = (unsigned short*)alloc((size_t)NN * HF * 2);

    hist_kernel<<<2 * G, 1024, 0, stream>>>(src, dst, hist_src, hist_dst);
    merge_dst_kernel<<<NB, 256, 0, stream>>>(hist_dst, cnt_dst, partial);
    merge_src_kernel<<<NB, 256, 0, stream>>>(hist_src, dinv);
    scan_partials_kernel<<<1, 256, 0, stream>>>(partial, offsets, row_ptr);
    scan_write_kernel<<<NB, 256, 0, stream>>>(cnt_dst, offsets, row_ptr);
    fill_kernel<<<G, 1024, 0, stream>>>(src, dst, hist_dst, row_ptr, col);
    gemm_kernel<<<(NN + 63) / 64, 256, 0, stream>>>(x, W, b, dinv, fbuf, gA);

    const int PB = (NN * HF + 255) / 256;
    // k=1: f stays in fbuf; g: gA -> gB
    prop_kernel<<<PB, 256, 0, stream>>>(row_ptr, col, dinv, gA, fbuf, HF, fbuf, HF, gB);
    // k=2: f: fbuf -> slot0; g: gB -> gA
    prop_kernel<<<PB, 256, 0, stream>>>(row_ptr, col, dinv, gB, fbuf, HF, out + 0 * HF, OUTF, gA);
    // k=3: slot0 -> slot1; g: gA -> gB
    prop_kernel<<<PB, 256, 0, stream>>>(row_ptr, col, dinv, gA, out + 0 * HF, OUTF, out + 1 * HF, OUTF, gB);
    // k=4: slot1 -> slot2; g: gB -> gA
    prop_kernel<<<PB, 256, 0, stream>>>(row_ptr, col, dinv, gB, out + 1 * HF, OUTF, out + 2 * HF, OUTF, gA);
    // k=5: slot2 -> slot3; g: gA -> gB
    prop_kernel<<<PB, 256, 0, stream>>>(row_ptr, col, dinv, gA, out + 2 * HF, OUTF, out + 3 * HF, OUTF, gB);
    // k=6: slot3 -> slot4; g unused
    prop_kernel<<<PB, 256, 0, stream>>>(row_ptr, col, dinv, gB, out + 3 * HF, OUTF, out + 4 * HF, OUTF, nullptr);

    ThetaM tm;
    compute_theta(tm);
    final_kernel<<<PB, 256, 0, stream>>>(out, tm);
}

// Round 6
// 343.259 us; speedup vs baseline: 1.8273x; 1.2654x over previous
//
#include <hip/hip_runtime.h>
#include <math.h>

#define NN 50000
#define NNH 25000          // NN/2 packed u32 bins
#define NE 800000
#define INF 256
#define HF 64
#define OUTF 320           // 5 * 64
#define NB ((NN + 255) / 256)   // 196 blocks for node-range kernels
#define G 128              // histogram slices per index array
#define SL (NE / G)        // 6250 edges per slice

typedef _Float16 half8 __attribute__((ext_vector_type(8)));
typedef float floatx4 __attribute__((ext_vector_type(4)));

// ---------------- fp16 helpers ----------------------------------------------
static __device__ __forceinline__ unsigned short f2h(float x) {
    _Float16 h = (_Float16)x;                 // v_cvt_f16_f32, RNE
    return *(unsigned short*)&h;
}
static __device__ __forceinline__ float h2f(unsigned short u) {
    _Float16 h = *(_Float16*)&u;
    return (float)h;                          // v_cvt_f32_f16
}

// ---------------- theta (computed on host each launch) ----------------------
struct ThetaM { float m[5][7]; };

static void compute_theta(ThetaM& tm) {
    const double e = 1.4;
    auto fact = [](int n) { double r = 1.0; for (int i = 2; i <= n; ++i) r *= i; return r; };
    for (int t = 0; t < 5; ++t) {
        int i = t + 2;              // i in [2,6]
        int mm = 6 - i;             // d - i + OFFSET
        double B = fact(i) * fact(6 - i) / fact(7);   // beta(i+1, 7-i)
        for (int k = 0; k < 7; ++k) tm.m[t][k] = 0.f;
        for (int j = 0; j <= mm; ++j) {
            double cb = fact(mm) / (fact(j) * fact(mm - j));
            double v = pow(1.0 / e, (double)i) * cb * pow(-1.0 / e, (double)j) / (e * B);
            tm.m[t][i + j] = (float)v;
        }
    }
}

// ---------------- histogram stage (no global atomics) -----------------------
__global__ __launch_bounds__(1024) void hist_kernel(const int* __restrict__ src,
                                                    const int* __restrict__ dst,
                                                    unsigned short* __restrict__ hist_src,
                                                    unsigned short* __restrict__ hist_dst) {
    __shared__ unsigned int h[NNH];
    int b = blockIdx.x;
    const int* arr = (b < G) ? dst : src;
    unsigned short* outp = (b < G) ? hist_dst : hist_src;
    int bb = (b < G) ? b : b - G;
    for (int i = threadIdx.x; i < NNH; i += 1024) h[i] = 0u;
    __syncthreads();
    int base = bb * SL;
    for (int i = threadIdx.x; i < SL; i += 1024) {
        int d = arr[base + i];
        atomicAdd(&h[d >> 1], 1u << ((d & 1) * 16));
    }
    __syncthreads();
    unsigned int* out32 = (unsigned int*)(outp + (size_t)bb * NN);
    for (int i = threadIdx.x; i < NNH; i += 1024) out32[i] = h[i];
}

// merge dst histograms: per node exclusive scan over blocks (in place), total
// count, and fused per-block partial sum for the global scan.
__global__ __launch_bounds__(256) void merge_dst_kernel(unsigned short* __restrict__ hist,
                                                        int* __restrict__ cnt,
                                                        int* __restrict__ partial) {
    __shared__ int s[256];
    int tid = threadIdx.x;
    int d = blockIdx.x * 256 + tid;
    int run = 0;
    if (d < NN) {
        for (int b = 0; b < G; ++b) {
            size_t idx = (size_t)b * NN + d;
            int v = hist[idx];
            hist[idx] = (unsigned short)run;   // exclusive per-block offset
            run += v;
        }
        cnt[d] = run;
    }
    s[tid] = run;
    __syncthreads();
    for (int off = 128; off > 0; off >>= 1) {
        if (tid < off) s[tid] += s[tid + off];
        __syncthreads();
    }
    if (tid == 0) partial[blockIdx.x] = s[0];
}

// merge src histograms: total degree -> dinv directly
__global__ __launch_bounds__(256) void merge_src_kernel(const unsigned short* __restrict__ hist,
                                                        float* __restrict__ dinv) {
    int d = blockIdx.x * 256 + threadIdx.x;
    if (d >= NN) return;
    int run = 0;
    for (int b = 0; b < G; ++b) run += hist[(size_t)b * NN + d];
    float dd = (float)run;
    if (dd < 1.f) dd = 1.f;
    dinv[d] = 1.0f / sqrtf(dd);
}

__global__ __launch_bounds__(256) void scan_partials_kernel(const int* __restrict__ partial,
                                                            int* __restrict__ offsets,
                                                            int* __restrict__ row_ptr) {
    __shared__ int s[256];
    int tid = threadIdx.x;
    s[tid] = (tid < NB) ? partial[tid] : 0;
    __syncthreads();
    for (int off = 1; off < 256; off <<= 1) {
        int t = (tid >= off) ? s[tid - off] : 0;
        __syncthreads();
        s[tid] += t;
        __syncthreads();
    }
    if (tid < NB) offsets[tid] = (tid == 0) ? 0 : s[tid - 1];
    if (tid == 0) row_ptr[NN] = NE;
}

__global__ __launch_bounds__(256) void scan_write_kernel(const int* __restrict__ cnt,
                                                         const int* __restrict__ offsets,
                                                         int* __restrict__ row_ptr) {
    __shared__ int s[256];
    int tid = threadIdx.x;
    int gid = blockIdx.x * 256 + tid;
    int c = (gid < NN) ? cnt[gid] : 0;
    s[tid] = c;
    __syncthreads();
    for (int off = 1; off < 256; off <<= 1) {
        int t = (tid >= off) ? s[tid - off] : 0;
        __syncthreads();
        s[tid] += t;
        __syncthreads();
    }
    if (gid < NN) row_ptr[gid] = offsets[blockIdx.x] + s[tid] - c;  // exclusive
}

// ---- fill: deterministic placement, LDS-rank only, no global atomics -------
__global__ __launch_bounds__(1024) void fill_kernel(const int* __restrict__ src,
                                                    const int* __restrict__ dst,
                                                    const unsigned short* __restrict__ hist_dst,
                                                    const int* __restrict__ row_ptr,
                                                    int* __restrict__ col) {
    __shared__ unsigned int cur[NNH];
    int b = blockIdx.x;
    for (int i = threadIdx.x; i < NNH; i += 1024) cur[i] = 0u;
    __syncthreads();
    int base = b * SL;
    const unsigned short* hrow = hist_dst + (size_t)b * NN;
    for (int i = threadIdx.x; i < SL; i += 1024) {
        int d = dst[base + i];
        int sh = (d & 1) * 16;
        unsigned int old = atomicAdd(&cur[d >> 1], 1u << sh);
        int rank = (int)((old >> sh) & 0xFFFFu);
        int pos = row_ptr[d] + (int)hrow[d] + rank;
        col[pos] = src[base + i];
    }
}

// ---- W prep: Wt[n][k] = fp16(W[k][n]), 64 x 256 ----------------------------
__global__ __launch_bounds__(256) void wprep_kernel(const float* __restrict__ W,
                                                    unsigned short* __restrict__ Wt) {
    int id = blockIdx.x * 256 + threadIdx.x;   // over 64*256
    if (id >= HF * INF) return;
    int n = id >> 8;       // 0..63
    int k = id & 255;      // 0..255
    Wt[id] = f2h(W[k * HF + n]);
}

// ---- MFMA fp16 GEMM: h = leaky_relu(x @ W + b); f fp32; g fp16(h*dinv) -----
// 64-row tile, 4 waves, each wave: 16 rows x 64 cols via 4 n-tiles of
// mfma_f32_16x16x32_f16 over K=256 (two 128-K LDS chunks of x).
// LDS: Wt 64x264 fp16 (33792B) + x 64x136 fp16 (17408B) = 51200B -> 3 blk/CU.
__global__ __launch_bounds__(256) void gemm_kernel(const float* __restrict__ x,
                                                   const unsigned short* __restrict__ Wt,
                                                   const float* __restrict__ b,
                                                   const float* __restrict__ dinv,
                                                   float* __restrict__ f,
                                                   unsigned short* __restrict__ g) {
    __shared__ _Float16 wls[64 * 264];   // row stride 264: 528B = 33*16B, banks +4/row
    __shared__ _Float16 xls[64 * 136];   // row stride 136: 272B = 17*16B, banks +4/row
    int tid = threadIdx.x;
    int row0 = blockIdx.x * 64;
    int wave = tid >> 6;
    int lane = tid & 63;
    int q = lane >> 4;        // quad 0..3
    int ln = lane & 15;

    // stage Wt: 64 rows x 32 x 16B chunks = 2048 chunks
    {
        const uint4* wg = (const uint4*)Wt;
        for (int i = 0; i < 8; ++i) {
            int l = tid + i * 256;
            int r = l >> 5, c = l & 31;
            *(uint4*)&wls[r * 264 + c * 8] = wg[l];
        }
    }

    floatx4 acc[4] = {{0.f,0.f,0.f,0.f},{0.f,0.f,0.f,0.f},{0.f,0.f,0.f,0.f},{0.f,0.f,0.f,0.f}};

    for (int ch = 0; ch < 2; ++ch) {
        __syncthreads();   // protect xls reuse (and Wt on first pass)
        // stage x chunk: 64 rows x 128 fp32 -> fp16
        for (int i = 0; i < 8; ++i) {
            int l = tid + i * 256;
            int r = l >> 5, c4 = (l & 31) * 4;
            int grow = row0 + r;
            float4 v = make_float4(0.f, 0.f, 0.f, 0.f);
            if (grow < NN) v = *(const float4*)&x[(size_t)grow * INF + ch * 128 + c4];
            ushort4 hv;
            hv.x = f2h(v.x); hv.y = f2h(v.y); hv.z = f2h(v.z); hv.w = f2h(v.w);
            *(ushort4*)&xls[r * 136 + c4] = hv;
        }
        __syncthreads();
        int m = wave * 16 + ln;
        #pragma unroll
        for (int kb4 = 0; kb4 < 4; ++kb4) {
            int kb = kb4 * 32;
            half8 a = *(const half8*)&xls[m * 136 + kb + q * 8];
            int kg = ch * 128 + kb + q * 8;
            #pragma unroll
            for (int t = 0; t < 4; ++t) {
                half8 bb = *(const half8*)&wls[(t * 16 + ln) * 264 + kg];
                acc[t] = __builtin_amdgcn_mfma_f32_16x16x32_f16(a, bb, acc[t], 0, 0, 0);
            }
        }
    }

    // epilogue: lane holds rows wave*16 + q*4 + r, col t*16 + ln
    float bias[4];
    #pragma unroll
    for (int t = 0; t < 4; ++t) bias[t] = b[t * 16 + ln];
    #pragma unroll
    for (int r = 0; r < 4; ++r) {
        int grow = row0 + wave * 16 + q * 4 + r;
        if (grow < NN) {
            float dv = dinv[grow];
            #pragma unroll
            for (int t = 0; t < 4; ++t) {
                float h = acc[t][r] + bias[t];
                h = (h > 0.f) ? h : 0.01f * h;
                int cidx = t * 16 + ln;
                f[(size_t)grow * HF + cidx] = h;
                g[(size_t)grow * HF + cidx] = f2h(h * dv);
            }
        }
    }
}

// prop: 32 lanes per node (2 nodes/wave), lane handles feature pair 2c,2c+1.
// msg = sum over in-edges of fp16 g_in rows; f_new = f_in - msg*dinv.
__global__ __launch_bounds__(256) void prop_kernel(const int* __restrict__ row_ptr,
                                                   const int* __restrict__ col,
                                                   const float* __restrict__ dinv,
                                                   const unsigned int* __restrict__ g_in,
                                                   const float* __restrict__ f_in, int fin_stride,
                                                   float* __restrict__ f_out, int fout_stride,
                                                   unsigned int* __restrict__ g_out) {
    int gidx = blockIdx.x * 256 + threadIdx.x;
    int wid = gidx >> 5;              // node
    int c2 = threadIdx.x & 31;        // feature pair
    if (wid >= NN) return;
    int start = row_ptr[wid];
    int end   = row_ptr[wid + 1];
    float s0 = 0.f, s1 = 0.f;
    int j = start;
    for (; j + 8 <= end; j += 8) {
        unsigned int u0 = g_in[col[j + 0] * 32 + c2];
        unsigned int u1 = g_in[col[j + 1] * 32 + c2];
        unsigned int u2 = g_in[col[j + 2] * 32 + c2];
        unsigned int u3 = g_in[col[j + 3] * 32 + c2];
        unsigned int u4 = g_in[col[j + 4] * 32 + c2];
        unsigned int u5 = g_in[col[j + 5] * 32 + c2];
        unsigned int u6 = g_in[col[j + 6] * 32 + c2];
        unsigned int u7 = g_in[col[j + 7] * 32 + c2];
        s0 += ((h2f(u0 & 0xFFFF) + h2f(u1 & 0xFFFF)) + (h2f(u2 & 0xFFFF) + h2f(u3 & 0xFFFF)))
            + ((h2f(u4 & 0xFFFF) + h2f(u5 & 0xFFFF)) + (h2f(u6 & 0xFFFF) + h2f(u7 & 0xFFFF)));
        s1 += ((h2f(u0 >> 16) + h2f(u1 >> 16)) + (h2f(u2 >> 16) + h2f(u3 >> 16)))
            + ((h2f(u4 >> 16) + h2f(u5 >> 16)) + (h2f(u6 >> 16) + h2f(u7 >> 16)));
    }
    for (; j < end; ++j) {
        unsigned int u = g_in[col[j] * 32 + c2];
        s0 += h2f(u & 0xFFFF);
        s1 += h2f(u >> 16);
    }
    float dv = dinv[wid];
    float2 fv = *(const float2*)&f_in[(size_t)wid * fin_stride + 2 * c2];
    float fx = fv.x - s0 * dv;
    float fy = fv.y - s1 * dv;
    *(float2*)&f_out[(size_t)wid * fout_stride + 2 * c2] = make_float2(fx, fy);
    if (g_out) g_out[wid * 32 + c2] = (unsigned int)f2h(fx * dv) | ((unsigned int)f2h(fy * dv) << 16);
}

// out slot t currently holds f_{t+2}; apply upper-triangular theta combo in place
__global__ __launch_bounds__(256) void final_kernel(float* __restrict__ out, ThetaM tm) {
    int idx = blockIdx.x * 256 + threadIdx.x;          // over NN*64
    if (idx >= NN * HF) return;
    int n = idx >> 6;
    int c = idx & 63;
    float v[5];
    #pragma unroll
    for (int j = 0; j < 5; ++j) v[j] = out[(size_t)n * OUTF + j * HF + c];
    #pragma unroll
    for (int t = 0; t < 5; ++t) {
        float o = 0.f;
        #pragma unroll
        for (int j = 0; j < 5; ++j) {
            if (j >= t) o += tm.m[t][j + 2] * v[j];    // k = j+2
        }
        out[(size_t)n * OUTF + t * HF + c] = o;
    }
}

// ---------------- launch -----------------------------------------------------
extern "C" void kernel_launch(void* const* d_in, const int* in_sizes, int n_in,
                              void* d_out, int out_size, void* d_ws, size_t ws_size,
                              hipStream_t stream) {
    const float* x  = (const float*)d_in[0];
    const float* W  = (const float*)d_in[1];
    const float* b  = (const float*)d_in[2];
    const int* src  = (const int*)d_in[3];
    const int* dst  = (const int*)d_in[4];
    float* out = (float*)d_out;

    char* ws = (char*)d_ws;
    size_t off = 0;
    auto alloc = [&](size_t bytes) -> void* {
        void* p = ws + off;
        off += (bytes + 255) & ~(size_t)255;
        return p;
    };
    unsigned short* hist_dst = (unsigned short*)alloc((size_t)G * NN * 2);
    unsigned short* hist_src = (unsigned short*)alloc((size_t)G * NN * 2);
    int*   cnt_dst = (int*)alloc((size_t)NN * 4);
    int*   row_ptr = (int*)alloc((size_t)(NN + 1) * 4);
    int*   partial = (int*)alloc((size_t)NB * 4);
    int*   offsets = (int*)alloc((size_t)NB * 4);
    float* dinv    = (float*)alloc((size_t)NN * 4);
    int*   col     = (int*)alloc((size_t)NE * 4);
    unsigned short* wt = (unsigned short*)alloc((size_t)HF * INF * 2);
    float* fbuf    = (float*)alloc((size_t)NN * HF * 4);
    unsigned short* gA = (unsigned short*)alloc((size_t)NN * HF * 2);
    unsigned short* gB = (unsigned short*)alloc((size_t)NN * HF * 2);

    hist_kernel<<<2 * G, 1024, 0, stream>>>(src, dst, hist_src, hist_dst);
    merge_dst_kernel<<<NB, 256, 0, stream>>>(hist_dst, cnt_dst, partial);
    merge_src_kernel<<<NB, 256, 0, stream>>>(hist_src, dinv);
    scan_partials_kernel<<<1, 256, 0, stream>>>(partial, offsets, row_ptr);
    scan_write_kernel<<<NB, 256, 0, stream>>>(cnt_dst, offsets, row_ptr);
    fill_kernel<<<G, 1024, 0, stream>>>(src, dst, hist_dst, row_ptr, col);
    wprep_kernel<<<(HF * INF + 255) / 256, 256, 0, stream>>>(W, wt);
    gemm_kernel<<<(NN + 63) / 64, 256, 0, stream>>>(x, wt, b, dinv, fbuf, gA);

    const int PB = (NN * 32 + 255) / 256;
    // k=1: f stays in fbuf; g: gA -> gB
    prop_kernel<<<PB, 256, 0, stream>>>(row_ptr, col, dinv, (unsigned int*)gA, fbuf, HF, fbuf, HF, (unsigned int*)gB);
    // k=2: f: fbuf -> slot0; g: gB -> gA
    prop_kernel<<<PB, 256, 0, stream>>>(row_ptr, col, dinv, (unsigned int*)gB, fbuf, HF, out + 0 * HF, OUTF, (unsigned int*)gA);
    // k=3: slot0 -> slot1; g: gA -> gB
    prop_kernel<<<PB, 256, 0, stream>>>(row_ptr, col, dinv, (unsigned int*)gA, out + 0 * HF, OUTF, out + 1 * HF, OUTF, (unsigned int*)gB);
    // k=4: slot1 -> slot2; g: gB -> gA
    prop_kernel<<<PB, 256, 0, stream>>>(row_ptr, col, dinv, (unsigned int*)gB, out + 1 * HF, OUTF, out + 2 * HF, OUTF, (unsigned int*)gA);
    // k=5: slot2 -> slot3; g: gA -> gB
    prop_kernel<<<PB, 256, 0, stream>>>(row_ptr, col, dinv, (unsigned int*)gA, out + 2 * HF, OUTF, out + 3 * HF, OUTF, (unsigned int*)gB);
    // k=6: slot3 -> slot4; g unused
    prop_kernel<<<PB, 256, 0, stream>>>(row_ptr, col, dinv, (unsigned int*)gB, out + 3 * HF, OUTF, out + 4 * HF, OUTF, nullptr);

    ThetaM tm;
    compute_theta(tm);
    final_kernel<<<(NN * HF + 255) / 256, 256, 0, stream>>>(out, tm);
}